// Round 2
// baseline (738.280 us; speedup 1.0000x reference)
//
#include <hip/hip_runtime.h>
#include <cstdint>
#include <cmath>

#define E_DIM 1024
#define FF_DIM 4096
#define B_DIM 4
#define S_DIM 2048
#define NTOK (B_DIM * S_DIM)  // 8192

typedef __bf16 bf16;
typedef __attribute__((ext_vector_type(8))) __bf16 bf16x8;
typedef __attribute__((ext_vector_type(4))) float f32x4;

// ---- async global->LDS, 16B per lane (HW: dest = wave-uniform base + lane*16)
__device__ __forceinline__ void gload_lds16(const void* g, void* l) {
  __builtin_amdgcn_global_load_lds(
      (const __attribute__((address_space(1))) unsigned int*)g,
      (__attribute__((address_space(3))) unsigned int*)l, 16, 0, 0);
}

__device__ __forceinline__ float waveRedSum(float v) {
#pragma unroll
  for (int o = 32; o > 0; o >>= 1) v += __shfl_xor(v, o, 64);
  return v;
}
__device__ __forceinline__ float waveRedMax(float v) {
#pragma unroll
  for (int o = 32; o > 0; o >>= 1) v = fmaxf(v, __shfl_xor(v, o, 64));
  return v;
}

// ---------------- fp32 -> bf16 convert (weights), 4 elems/thread -------------
__global__ __launch_bounds__(256) void cvt_k(const float* __restrict__ in,
                                             bf16* __restrict__ out, int n4) {
  int i = blockIdx.x * 256 + threadIdx.x;
  if (i < n4) {
    float4 v = reinterpret_cast<const float4*>(in)[i];
    bf16* o = out + (size_t)i * 4;
    o[0] = (bf16)v.x; o[1] = (bf16)v.y; o[2] = (bf16)v.z; o[3] = (bf16)v.w;
  }
}

// ---------------- LayerNorm over E=1024, one block (256 thr) per row ---------
template <typename OutT>
__global__ __launch_bounds__(256) void layernorm_k(const float* __restrict__ x,
                                                   OutT* __restrict__ out,
                                                   const float* __restrict__ g,
                                                   const float* __restrict__ b) {
  const int row = blockIdx.x;
  const int tid = threadIdx.x;
  const float4 v = reinterpret_cast<const float4*>(x + (size_t)row * E_DIM)[tid];
  float s = v.x + v.y + v.z + v.w;
  float q = v.x * v.x + v.y * v.y + v.z * v.z + v.w * v.w;
  s = waveRedSum(s);
  q = waveRedSum(q);
  __shared__ float sa[4], sb[4];
  const int lane = tid & 63, wid = tid >> 6;
  if (lane == 0) { sa[wid] = s; sb[wid] = q; }
  __syncthreads();
  s = sa[0] + sa[1] + sa[2] + sa[3];
  q = sb[0] + sb[1] + sb[2] + sb[3];
  const float mean = s * (1.0f / E_DIM);
  const float var = q * (1.0f / E_DIM) - mean * mean;
  const float rstd = rsqrtf(var + 1e-5f);
  const int c = tid * 4;
  OutT* op = out + (size_t)row * E_DIM + c;
  const float vv[4] = {v.x, v.y, v.z, v.w};
#pragma unroll
  for (int j = 0; j < 4; ++j)
    op[j] = (OutT)((vv[j] - mean) * rstd * g[c + j] + b[c + j]);
}

// ---------------- row softmax over S=2048, in-place bf16 ---------------------
// Block 256: each thread owns 8 contiguous bf16 (exclusive) -> no WAR hazard.
__global__ __launch_bounds__(256) void softmax_k(bf16* __restrict__ scores) {
  const int row = blockIdx.x;
  bf16* rp = scores + (size_t)row * S_DIM;
  const int tid = threadIdx.x;
  const int lane = tid & 63, wid = tid >> 6;
  bf16x8 v8 = *reinterpret_cast<const bf16x8*>(rp + tid * 8);
  float v[8];
#pragma unroll
  for (int j = 0; j < 8; ++j) v[j] = (float)v8[j];
  float mx = v[0];
#pragma unroll
  for (int j = 1; j < 8; ++j) mx = fmaxf(mx, v[j]);
  mx = waveRedMax(mx);
  __shared__ float sm_[4], ss_[4];
  if (lane == 0) sm_[wid] = mx;
  __syncthreads();
  mx = fmaxf(fmaxf(sm_[0], sm_[1]), fmaxf(sm_[2], sm_[3]));
  float e[8];
  float s = 0.f;
#pragma unroll
  for (int j = 0; j < 8; ++j) { e[j] = __expf(v[j] - mx); s += e[j]; }
  s = waveRedSum(s);
  if (lane == 0) ss_[wid] = s;
  __syncthreads();
  s = ss_[0] + ss_[1] + ss_[2] + ss_[3];
  const float inv = 1.0f / s;
  bf16x8 o;
#pragma unroll
  for (int j = 0; j < 8; ++j) o[j] = (bf16)(e[j] * inv);
  *reinterpret_cast<bf16x8*>(rp + tid * 8) = o;
}

// ---------------- bf16 transpose [S][E] -> [E][S] per batch ------------------
__global__ __launch_bounds__(256) void transpose_k(const bf16* __restrict__ in,
                                                   bf16* __restrict__ out) {
  __shared__ bf16 t[32][33];
  const int b = blockIdx.z;
  const bf16* ip = in + (size_t)b * S_DIM * E_DIM;
  bf16* op = out + (size_t)b * S_DIM * E_DIM;
  const int e0 = blockIdx.x * 32, s0 = blockIdx.y * 32;
  const int tx = threadIdx.x & 31, ty = threadIdx.x >> 5;  // 32 x 8
#pragma unroll
  for (int r = 0; r < 32; r += 8) t[ty + r][tx] = ip[(size_t)(s0 + ty + r) * E_DIM + e0 + tx];
  __syncthreads();
#pragma unroll
  for (int r = 0; r < 32; r += 8) op[(size_t)(e0 + ty + r) * S_DIM + s0 + tx] = t[tx][ty + r];
}

// ---------------- GEMM: C = scale*(A @ Bt^T) + bias (+resid) (+relu) ---------
// A: M x K (row stride lda, bf16, K-contig). Bt: N x K (row stride ldb).
// 128x128 tile, BK=32, 4 waves in 2x2, each wave 64x64 = 4x4 16x16 frags.
template <typename OutT, bool RELU>
__global__ __launch_bounds__(256) void gemm_bt_k(
    const bf16* __restrict__ A, int lda, const bf16* __restrict__ Bt, int ldb,
    OutT* __restrict__ C, int ldc, int M, int N, int K,
    const float* __restrict__ bias, const float* __restrict__ resid, int ldr,
    float scale) {
  __shared__ bf16 lsA[128 * 32];
  __shared__ bf16 lsB[128 * 32];
  const int tid = threadIdx.x;
  const int lane = tid & 63;
  const int wid = tid >> 6;
  const int wr = wid >> 1, wc = wid & 1;
  const int m0 = blockIdx.y * 128, n0 = blockIdx.x * 128;

  f32x4 acc[4][4] = {};

  for (int k0 = 0; k0 < K; k0 += 32) {
#pragma unroll
    for (int c = 0; c < 2; ++c) {
      const int chunk = c * 256 + tid;      // 512 chunks of 16B per 8KB tile
      const int r = chunk >> 2;             // 4 chunks per 32-elem row
      const int col = (chunk & 3) * 8;
      gload_lds16(A + (size_t)(m0 + r) * lda + k0 + col,
                  &lsA[(c * 256 + wid * 64) * 8]);
      gload_lds16(Bt + (size_t)(n0 + r) * ldb + k0 + col,
                  &lsB[(c * 256 + wid * 64) * 8]);
    }
    __syncthreads();
    bf16x8 af[4], bfr[4];
#pragma unroll
    for (int f = 0; f < 4; ++f) {
      af[f] = *reinterpret_cast<const bf16x8*>(
          &lsA[(wr * 64 + f * 16 + (lane & 15)) * 32 + (lane >> 4) * 8]);
      bfr[f] = *reinterpret_cast<const bf16x8*>(
          &lsB[(wc * 64 + f * 16 + (lane & 15)) * 32 + (lane >> 4) * 8]);
    }
#pragma unroll
    for (int fm = 0; fm < 4; ++fm)
#pragma unroll
      for (int fn = 0; fn < 4; ++fn)
        acc[fm][fn] = __builtin_amdgcn_mfma_f32_16x16x32_bf16(
            af[fm], bfr[fn], acc[fm][fn], 0, 0, 0);
    __syncthreads();
  }

  const int rb = m0 + wr * 64;
  const int cb = n0 + wc * 64;
#pragma unroll
  for (int fn = 0; fn < 4; ++fn) {
    const int col = cb + fn * 16 + (lane & 15);
    const float bv = bias ? bias[col] : 0.0f;
#pragma unroll
    for (int fm = 0; fm < 4; ++fm) {
#pragma unroll
      for (int i = 0; i < 4; ++i) {
        const int row = rb + fm * 16 + (lane >> 4) * 4 + i;
        float v = acc[fm][fn][i] * scale + bv;
        if (resid) v += resid[(size_t)row * ldr + col];
        if (RELU) v = fmaxf(v, 0.0f);
        C[(size_t)row * ldc + col] = (OutT)v;
      }
    }
  }
}

// =============================================================================
extern "C" void kernel_launch(void* const* d_in, const int* in_sizes, int n_in,
                              void* d_out, int out_size, void* d_ws,
                              size_t ws_size, hipStream_t stream) {
  const float* src = (const float*)d_in[0];
  const float* Wq_w = (const float*)d_in[1];
  const float* Wq_b = (const float*)d_in[2];
  const float* Wk_w = (const float*)d_in[3];
  const float* Wk_b = (const float*)d_in[4];
  const float* Wv_w = (const float*)d_in[5];
  const float* Wv_b = (const float*)d_in[6];
  const float* Wo_w = (const float*)d_in[7];
  const float* Wo_b = (const float*)d_in[8];
  const float* W1_w = (const float*)d_in[9];
  const float* W1_b = (const float*)d_in[10];
  const float* W2_w = (const float*)d_in[11];
  const float* W2_b = (const float*)d_in[12];
  const float* g1 = (const float*)d_in[13];
  const float* b1 = (const float*)d_in[14];
  const float* g2 = (const float*)d_in[15];
  const float* b2 = (const float*)d_in[16];
  const float* g3 = (const float*)d_in[17];
  const float* b3 = (const float*)d_in[18];
  float* out = (float*)d_out;
  (void)ws_size; (void)in_sizes; (void)n_in; (void)out_size;

  // ---- workspace layout: peak 120 MB, heavy aliasing (lifetimes verified) ---
  const size_t MB = 1ull << 20;
  char* ws = (char*)d_ws;
  bf16* wq = (bf16*)(ws + 0 * MB);     // 2 MB
  bf16* wk = (bf16*)(ws + 2 * MB);     // 2 MB
  bf16* wv = (bf16*)(ws + 4 * MB);     // 2 MB
  bf16* wo = (bf16*)(ws + 6 * MB);     // 2 MB
  bf16* w1 = (bf16*)(ws + 8 * MB);     // 8 MB
  bf16* w2 = (bf16*)(ws + 16 * MB);    // 8 MB
  bf16* Qb = (bf16*)(ws + 24 * MB);    // 16 MB; later: ctx
  bf16* Kb = (bf16*)(ws + 40 * MB);    // 16 MB; later: hn
  bf16* Vb = (bf16*)(ws + 56 * MB);    // 16 MB; later: part of f1
  bf16* Vt = (bf16*)(ws + 72 * MB);    // 16 MB; later: part of f1
  bf16* scoresB = (bf16*)(ws + 88 * MB); // 32 MB (bf16 scores/P)
  bf16* xln = (bf16*)(ws + 88 * MB);   // 16 MB, dead before scores written
  bf16* ctx = Qb;                       // alias (Qb dead after QK^T)
  bf16* hn = Kb;                        // alias (Kb dead after QK^T)
  bf16* f1 = Vb;                        // 64 MB span [56..120) (all dead at FF1)
  float* h = out;                       // residual stream lives in d_out

  // weights -> bf16
  cvt_k<<<(E_DIM * E_DIM / 4 + 255) / 256, 256, 0, stream>>>(Wq_w, wq, E_DIM * E_DIM / 4);
  cvt_k<<<(E_DIM * E_DIM / 4 + 255) / 256, 256, 0, stream>>>(Wk_w, wk, E_DIM * E_DIM / 4);
  cvt_k<<<(E_DIM * E_DIM / 4 + 255) / 256, 256, 0, stream>>>(Wv_w, wv, E_DIM * E_DIM / 4);
  cvt_k<<<(E_DIM * E_DIM / 4 + 255) / 256, 256, 0, stream>>>(Wo_w, wo, E_DIM * E_DIM / 4);
  cvt_k<<<(FF_DIM * E_DIM / 4 + 255) / 256, 256, 0, stream>>>(W1_w, w1, FF_DIM * E_DIM / 4);
  cvt_k<<<(FF_DIM * E_DIM / 4 + 255) / 256, 256, 0, stream>>>(W2_w, w2, FF_DIM * E_DIM / 4);

  // LN1
  layernorm_k<bf16><<<NTOK, 256, 0, stream>>>(src, xln, g1, b1);

  // QKV projections
  dim3 gQKV(E_DIM / 128, NTOK / 128);
  gemm_bt_k<bf16, false><<<gQKV, 256, 0, stream>>>(xln, E_DIM, wq, E_DIM, Qb, E_DIM,
      NTOK, E_DIM, E_DIM, Wq_b, nullptr, 0, 1.0f);
  gemm_bt_k<bf16, false><<<gQKV, 256, 0, stream>>>(xln, E_DIM, wk, E_DIM, Kb, E_DIM,
      NTOK, E_DIM, E_DIM, Wk_b, nullptr, 0, 1.0f);
  gemm_bt_k<bf16, false><<<gQKV, 256, 0, stream>>>(xln, E_DIM, wv, E_DIM, Vb, E_DIM,
      NTOK, E_DIM, E_DIM, Wv_b, nullptr, 0, 1.0f);

  // scores[b] = (Q K^T) / 32 -> bf16 (xln region is dead now)
  dim3 gSc(S_DIM / 128, S_DIM / 128);
  for (int b = 0; b < B_DIM; ++b) {
    gemm_bt_k<bf16, false><<<gSc, 256, 0, stream>>>(
        Qb + (size_t)b * S_DIM * E_DIM, E_DIM, Kb + (size_t)b * S_DIM * E_DIM, E_DIM,
        scoresB + (size_t)b * S_DIM * S_DIM, S_DIM, S_DIM, S_DIM, E_DIM,
        nullptr, nullptr, 0, 1.0f / 32.0f);
  }

  // softmax rows, in-place bf16
  softmax_k<<<B_DIM * S_DIM, 256, 0, stream>>>(scoresB);

  // V transpose per batch
  transpose_k<<<dim3(E_DIM / 32, S_DIM / 32, B_DIM), 256, 0, stream>>>(Vb, Vt);

  // ctx[b] = P V   (writes over Qb; P + Vt still live)
  dim3 gPV(E_DIM / 128, S_DIM / 128);
  for (int b = 0; b < B_DIM; ++b) {
    gemm_bt_k<bf16, false><<<gPV, 256, 0, stream>>>(
        scoresB + (size_t)b * S_DIM * S_DIM, S_DIM,
        Vt + (size_t)b * S_DIM * E_DIM, S_DIM, ctx + (size_t)b * S_DIM * E_DIM, E_DIM,
        S_DIM, E_DIM, S_DIM, nullptr, nullptr, 0, 1.0f);
  }

  // h = src + ctx @ Wo^T + bo   (fp32, into d_out)
  gemm_bt_k<float, false><<<gQKV, 256, 0, stream>>>(ctx, E_DIM, wo, E_DIM, h, E_DIM,
      NTOK, E_DIM, E_DIM, Wo_b, src, E_DIM, 1.0f);

  // LN2 (reads h=d_out, writes hn over Kb)
  layernorm_k<bf16><<<NTOK, 256, 0, stream>>>(h, hn, g2, b2);

  // f1 = relu(hn @ W1^T + b1)   (writes over Vb/Vt/scores span)
  dim3 gF1(FF_DIM / 128, NTOK / 128);
  gemm_bt_k<bf16, true><<<gF1, 256, 0, stream>>>(hn, E_DIM, w1, E_DIM, f1, FF_DIM,
      NTOK, FF_DIM, E_DIM, W1_b, nullptr, 0, 1.0f);

  // out = h + f1 @ W2^T + b2   (fp32, resid == C: per-element read-then-write)
  gemm_bt_k<float, false><<<gQKV, 256, 0, stream>>>(f1, FF_DIM, w2, FF_DIM, out, E_DIM,
      NTOK, E_DIM, FF_DIM, W2_b, h, E_DIM, 1.0f);

  // LN3 in-place
  layernorm_k<float><<<NTOK, 256, 0, stream>>>(out, out, g3, b3);
}

// Round 3
// 453.096 us; speedup vs baseline: 1.6294x; 1.6294x over previous
//
#include <hip/hip_runtime.h>
#include <cstdint>
#include <cmath>

#define E_DIM 1024
#define FF_DIM 4096
#define B_DIM 4
#define S_DIM 2048
#define NTOK (B_DIM * S_DIM)  // 8192

typedef __bf16 bf16;
typedef __attribute__((ext_vector_type(8))) __bf16 bf16x8;
typedef __attribute__((ext_vector_type(4))) float f32x4;

// ---- async global->LDS, 16B per lane (HW: dest = wave-uniform base + lane*16)
__device__ __forceinline__ void gload_lds16(const void* g, void* l) {
  __builtin_amdgcn_global_load_lds(
      (const __attribute__((address_space(1))) unsigned int*)g,
      (__attribute__((address_space(3))) unsigned int*)l, 16, 0, 0);
}

__device__ __forceinline__ float waveRedSum(float v) {
#pragma unroll
  for (int o = 32; o > 0; o >>= 1) v += __shfl_xor(v, o, 64);
  return v;
}
__device__ __forceinline__ float waveRedMax(float v) {
#pragma unroll
  for (int o = 32; o > 0; o >>= 1) v = fmaxf(v, __shfl_xor(v, o, 64));
  return v;
}

// ---------------- fp32 -> bf16 convert (weights), 4 elems/thread -------------
__global__ __launch_bounds__(256) void cvt_k(const float* __restrict__ in,
                                             bf16* __restrict__ out, int n4) {
  int i = blockIdx.x * 256 + threadIdx.x;
  if (i < n4) {
    float4 v = reinterpret_cast<const float4*>(in)[i];
    bf16* o = out + (size_t)i * 4;
    o[0] = (bf16)v.x; o[1] = (bf16)v.y; o[2] = (bf16)v.z; o[3] = (bf16)v.w;
  }
}

// ---------------- LayerNorm over E=1024, one block (256 thr) per row ---------
template <typename OutT>
__global__ __launch_bounds__(256) void layernorm_k(const float* __restrict__ x,
                                                   OutT* __restrict__ out,
                                                   const float* __restrict__ g,
                                                   const float* __restrict__ b) {
  const int row = blockIdx.x;
  const int tid = threadIdx.x;
  const float4 v = reinterpret_cast<const float4*>(x + (size_t)row * E_DIM)[tid];
  float s = v.x + v.y + v.z + v.w;
  float q = v.x * v.x + v.y * v.y + v.z * v.z + v.w * v.w;
  s = waveRedSum(s);
  q = waveRedSum(q);
  __shared__ float sa[4], sb[4];
  const int lane = tid & 63, wid = tid >> 6;
  if (lane == 0) { sa[wid] = s; sb[wid] = q; }
  __syncthreads();
  s = sa[0] + sa[1] + sa[2] + sa[3];
  q = sb[0] + sb[1] + sb[2] + sb[3];
  const float mean = s * (1.0f / E_DIM);
  const float var = q * (1.0f / E_DIM) - mean * mean;
  const float rstd = rsqrtf(var + 1e-5f);
  const int c = tid * 4;
  OutT* op = out + (size_t)row * E_DIM + c;
  const float vv[4] = {v.x, v.y, v.z, v.w};
#pragma unroll
  for (int j = 0; j < 4; ++j)
    op[j] = (OutT)((vv[j] - mean) * rstd * g[c + j] + b[c + j]);
}

// ---------------- row softmax over S=2048, in-place bf16 ---------------------
__global__ __launch_bounds__(256) void softmax_k(bf16* __restrict__ scores) {
  const int row = blockIdx.x;
  bf16* rp = scores + (size_t)row * S_DIM;
  const int tid = threadIdx.x;
  const int lane = tid & 63, wid = tid >> 6;
  bf16x8 v8 = *reinterpret_cast<const bf16x8*>(rp + tid * 8);
  float v[8];
#pragma unroll
  for (int j = 0; j < 8; ++j) v[j] = (float)v8[j];
  float mx = v[0];
#pragma unroll
  for (int j = 1; j < 8; ++j) mx = fmaxf(mx, v[j]);
  mx = waveRedMax(mx);
  __shared__ float sm_[4], ss_[4];
  if (lane == 0) sm_[wid] = mx;
  __syncthreads();
  mx = fmaxf(fmaxf(sm_[0], sm_[1]), fmaxf(sm_[2], sm_[3]));
  float e[8];
  float s = 0.f;
#pragma unroll
  for (int j = 0; j < 8; ++j) { e[j] = __expf(v[j] - mx); s += e[j]; }
  s = waveRedSum(s);
  if (lane == 0) ss_[wid] = s;
  __syncthreads();
  s = ss_[0] + ss_[1] + ss_[2] + ss_[3];
  const float inv = 1.0f / s;
  bf16x8 o;
#pragma unroll
  for (int j = 0; j < 8; ++j) o[j] = (bf16)(e[j] * inv);
  *reinterpret_cast<bf16x8*>(rp + tid * 8) = o;
}

// ---------------- bf16 transpose [S][E] -> [E][S] per batch ------------------
__global__ __launch_bounds__(256) void transpose_k(const bf16* __restrict__ in,
                                                   bf16* __restrict__ out) {
  __shared__ bf16 t[32][33];
  const int b = blockIdx.z;
  const bf16* ip = in + (size_t)b * S_DIM * E_DIM;
  bf16* op = out + (size_t)b * S_DIM * E_DIM;
  const int e0 = blockIdx.x * 32, s0 = blockIdx.y * 32;
  const int tx = threadIdx.x & 31, ty = threadIdx.x >> 5;  // 32 x 8
#pragma unroll
  for (int r = 0; r < 32; r += 8) t[ty + r][tx] = ip[(size_t)(s0 + ty + r) * E_DIM + e0 + tx];
  __syncthreads();
#pragma unroll
  for (int r = 0; r < 32; r += 8) op[(size_t)(e0 + ty + r) * S_DIM + s0 + tx] = t[tx][ty + r];
}

// ============================================================================
// 256x128 8-wave GEMM, BK=64, 3-deep tile pipeline, counted vmcnt, T2 swizzle.
// C = scale*(A @ Bt^T) + bias (+resid) (+relu).  A: MxK (lda), Bt: NxK (ldb).
// LDS: A bufs 3x32KB @0, B bufs 3x16KB @98304. Total 144 KB.
// Swizzle: LDS row = 64 bf16 = 128 B; byte ^= (row&7)<<4, applied as
// inverse-swizzled GLOBAL source (linear gload_lds dest) + swizzled ds_read.
// ============================================================================
__device__ __forceinline__ void stage_chunk(const bf16* __restrict__ A, int lda,
                                            const bf16* __restrict__ Bt, int ldb,
                                            char* smem, int m0, int n0, int t,
                                            int c, int tid, int wid) {
  const int rb = t % 3;
  const int kk = t * 64;
  const int r = tid >> 3;                    // 0..63 row within chunk
  const int col8 = (tid & 7) ^ (r & 7);      // inverse swizzle on source
  if (c < 4) {
    gload_lds16(A + (size_t)(m0 + c * 64 + r) * lda + kk + col8 * 8,
                smem + rb * 32768 + c * 8192 + wid * 1024);
  } else {
    gload_lds16(Bt + (size_t)(n0 + (c - 4) * 64 + r) * ldb + kk + col8 * 8,
                smem + 98304 + rb * 16384 + (c - 4) * 8192 + wid * 1024);
  }
}

template <typename OutT, bool RELU>
__global__ __launch_bounds__(512) void gemm256_k(
    const bf16* __restrict__ A0, int lda, const bf16* __restrict__ Bt0, int ldb,
    OutT* __restrict__ C0, int ldc, int M, int N, int K,
    const float* __restrict__ bias, const float* __restrict__ resid, int ldr,
    float scale, size_t sAz, size_t sBz, size_t sCz) {
  __shared__ __align__(16) char smem[147456];
  const int tid = threadIdx.x;
  const int lane = tid & 63;
  const int wid = tid >> 6;   // 0..7
  const int wr = wid >> 2;    // 0..1 (M)
  const int wc = wid & 3;     // 0..3 (N)

  const bf16* A = A0 + (size_t)blockIdx.z * sAz;
  const bf16* Bt = Bt0 + (size_t)blockIdx.z * sBz;
  OutT* C = C0 + (size_t)blockIdx.z * sCz;

  // T1: bijective XCD-aware remap (m204)
  const int gx = gridDim.x;
  const int nwg = gx * gridDim.y;
  int wg = blockIdx.y * gx + blockIdx.x;
  {
    const int q = nwg >> 3, r8 = nwg & 7;
    const int xcd = wg & 7, lin = wg >> 3;
    wg = (xcd < r8 ? xcd * (q + 1) : r8 * (q + 1) + (xcd - r8) * q) + lin;
  }
  const int m0 = (wg / gx) * 256;
  const int n0 = (wg % gx) * 128;

  f32x4 acc[2][4][2] = {};

  // prologue: stage tiles 0 and 1 (6 chunks each)
#pragma unroll
  for (int c = 0; c < 6; ++c) stage_chunk(A, lda, Bt, ldb, smem, m0, n0, 0, c, tid, wid);
#pragma unroll
  for (int c = 0; c < 6; ++c) stage_chunk(A, lda, Bt, ldb, smem, m0, n0, 1, c, tid, wid);
  asm volatile("s_waitcnt vmcnt(6)" ::: "memory");  // tile0 landed; tile1 in flight
  __builtin_amdgcn_s_barrier();

  const int NT = K >> 6;
  for (int t = 0; t < NT; ++t) {
    const int rb = t % 3;
    const char* lA = smem + rb * 32768;
    const char* lB = smem + 98304 + rb * 16384;
#pragma unroll
    for (int mh = 0; mh < 2; ++mh) {
      // --- ds_read this phase's fragments (12 x ds_read_b128, swizzled) ---
      bf16x8 af[4][2], bfv[2][2];
#pragma unroll
      for (int fm = 0; fm < 4; ++fm) {
        const int row = wr * 128 + mh * 64 + fm * 16 + (lane & 15);
#pragma unroll
        for (int ks = 0; ks < 2; ++ks) {
          const int g = ((ks << 2) | (lane >> 4)) ^ (row & 7);
          af[fm][ks] = *reinterpret_cast<const bf16x8*>(lA + row * 128 + g * 16);
        }
      }
#pragma unroll
      for (int fn = 0; fn < 2; ++fn) {
        const int row = wc * 32 + fn * 16 + (lane & 15);
#pragma unroll
        for (int ks = 0; ks < 2; ++ks) {
          const int g = ((ks << 2) | (lane >> 4)) ^ (row & 7);
          bfv[fn][ks] = *reinterpret_cast<const bf16x8*>(lB + row * 128 + g * 16);
        }
      }
      // --- stage 3 chunks of tile t+2 into buf (t+2)%3 (disjoint from t,t+1)
      if (t + 2 < NT) {
#pragma unroll
        for (int c = 0; c < 3; ++c)
          stage_chunk(A, lda, Bt, ldb, smem, m0, n0, t + 2, mh * 3 + c, tid, wid);
      }
      __builtin_amdgcn_s_barrier();
      __builtin_amdgcn_s_setprio(1);
#pragma unroll
      for (int fm = 0; fm < 4; ++fm)
#pragma unroll
        for (int fn = 0; fn < 2; ++fn) {
          acc[mh][fm][fn] = __builtin_amdgcn_mfma_f32_16x16x32_bf16(
              af[fm][0], bfv[fn][0], acc[mh][fm][fn], 0, 0, 0);
          acc[mh][fm][fn] = __builtin_amdgcn_mfma_f32_16x16x32_bf16(
              af[fm][1], bfv[fn][1], acc[mh][fm][fn], 0, 0, 0);
        }
      __builtin_amdgcn_s_setprio(0);
      if (mh == 1) {
        // tile boundary: ensure tile t+1 landed before its reads (after bar).
        // counted: tile t+2's 6 stage-loads may stay in flight.
        if (t + 2 < NT) {
          asm volatile("s_waitcnt vmcnt(6)" ::: "memory");
        } else {
          asm volatile("s_waitcnt vmcnt(0)" ::: "memory");
        }
      }
      __builtin_amdgcn_s_barrier();
    }
  }

  // --------------------------- epilogue -------------------------------------
#pragma unroll
  for (int mh = 0; mh < 2; ++mh)
#pragma unroll
    for (int fn = 0; fn < 2; ++fn) {
      const int col = n0 + wc * 32 + fn * 16 + (lane & 15);
      const float bv = bias ? bias[col] : 0.0f;
#pragma unroll
      for (int fm = 0; fm < 4; ++fm)
#pragma unroll
        for (int i = 0; i < 4; ++i) {
          const int row = m0 + wr * 128 + mh * 64 + fm * 16 + (lane >> 4) * 4 + i;
          float v = acc[mh][fm][fn][i] * scale + bv;
          if (resid) v += resid[(size_t)row * ldr + col];
          if (RELU) v = fmaxf(v, 0.0f);
          C[(size_t)row * ldc + col] = (OutT)v;
        }
    }
}

// =============================================================================
extern "C" void kernel_launch(void* const* d_in, const int* in_sizes, int n_in,
                              void* d_out, int out_size, void* d_ws,
                              size_t ws_size, hipStream_t stream) {
  const float* src = (const float*)d_in[0];
  const float* Wq_w = (const float*)d_in[1];
  const float* Wq_b = (const float*)d_in[2];
  const float* Wk_w = (const float*)d_in[3];
  const float* Wk_b = (const float*)d_in[4];
  const float* Wv_w = (const float*)d_in[5];
  const float* Wv_b = (const float*)d_in[6];
  const float* Wo_w = (const float*)d_in[7];
  const float* Wo_b = (const float*)d_in[8];
  const float* W1_w = (const float*)d_in[9];
  const float* W1_b = (const float*)d_in[10];
  const float* W2_w = (const float*)d_in[11];
  const float* W2_b = (const float*)d_in[12];
  const float* g1 = (const float*)d_in[13];
  const float* b1 = (const float*)d_in[14];
  const float* g2 = (const float*)d_in[15];
  const float* b2 = (const float*)d_in[16];
  const float* g3 = (const float*)d_in[17];
  const float* b3 = (const float*)d_in[18];
  float* out = (float*)d_out;
  (void)ws_size; (void)in_sizes; (void)n_in; (void)out_size;

  // ---- workspace layout: peak 120 MB, heavy aliasing (lifetimes verified) ---
  const size_t MB = 1ull << 20;
  char* ws = (char*)d_ws;
  bf16* wq = (bf16*)(ws + 0 * MB);       // 2 MB
  bf16* wk = (bf16*)(ws + 2 * MB);       // 2 MB
  bf16* wv = (bf16*)(ws + 4 * MB);       // 2 MB
  bf16* wo = (bf16*)(ws + 6 * MB);       // 2 MB
  bf16* w1 = (bf16*)(ws + 8 * MB);       // 8 MB
  bf16* w2 = (bf16*)(ws + 16 * MB);      // 8 MB
  bf16* Qb = (bf16*)(ws + 24 * MB);      // 16 MB; later: ctx
  bf16* Kb = (bf16*)(ws + 40 * MB);      // 16 MB; later: hn
  bf16* Vb = (bf16*)(ws + 56 * MB);      // 16 MB; later: part of f1
  bf16* Vt = (bf16*)(ws + 72 * MB);      // 16 MB; later: part of f1
  bf16* scoresB = (bf16*)(ws + 88 * MB); // 32 MB (bf16 scores/P)
  bf16* xln = (bf16*)(ws + 88 * MB);     // 16 MB, dead before scores written
  bf16* ctx = Qb;                        // alias (Qb dead after QK^T)
  bf16* hn = Kb;                         // alias (Kb dead after QK^T)
  bf16* f1 = Vb;                         // 64 MB span [56..120)
  float* h = out;                        // residual stream lives in d_out

  // weights -> bf16
  cvt_k<<<(E_DIM * E_DIM / 4 + 255) / 256, 256, 0, stream>>>(Wq_w, wq, E_DIM * E_DIM / 4);
  cvt_k<<<(E_DIM * E_DIM / 4 + 255) / 256, 256, 0, stream>>>(Wk_w, wk, E_DIM * E_DIM / 4);
  cvt_k<<<(E_DIM * E_DIM / 4 + 255) / 256, 256, 0, stream>>>(Wv_w, wv, E_DIM * E_DIM / 4);
  cvt_k<<<(E_DIM * E_DIM / 4 + 255) / 256, 256, 0, stream>>>(Wo_w, wo, E_DIM * E_DIM / 4);
  cvt_k<<<(FF_DIM * E_DIM / 4 + 255) / 256, 256, 0, stream>>>(W1_w, w1, FF_DIM * E_DIM / 4);
  cvt_k<<<(FF_DIM * E_DIM / 4 + 255) / 256, 256, 0, stream>>>(W2_w, w2, FF_DIM * E_DIM / 4);

  // LN1
  layernorm_k<bf16><<<NTOK, 256, 0, stream>>>(src, xln, g1, b1);

  // QKV projections: M=8192, N=1024, K=1024
  dim3 gQKV(E_DIM / 128, NTOK / 256);
  gemm256_k<bf16, false><<<gQKV, 512, 0, stream>>>(xln, E_DIM, wq, E_DIM, Qb, E_DIM,
      NTOK, E_DIM, E_DIM, Wq_b, nullptr, 0, 1.0f, 0, 0, 0);
  gemm256_k<bf16, false><<<gQKV, 512, 0, stream>>>(xln, E_DIM, wk, E_DIM, Kb, E_DIM,
      NTOK, E_DIM, E_DIM, Wk_b, nullptr, 0, 1.0f, 0, 0, 0);
  gemm256_k<bf16, false><<<gQKV, 512, 0, stream>>>(xln, E_DIM, wv, E_DIM, Vb, E_DIM,
      NTOK, E_DIM, E_DIM, Wv_b, nullptr, 0, 1.0f, 0, 0, 0);

  // scores[b] = (Q K^T) / 32 -> bf16, batched over z
  dim3 gSc(S_DIM / 128, S_DIM / 256, B_DIM);
  gemm256_k<bf16, false><<<gSc, 512, 0, stream>>>(
      Qb, E_DIM, Kb, E_DIM, scoresB, S_DIM, S_DIM, S_DIM, E_DIM,
      nullptr, nullptr, 0, 1.0f / 32.0f,
      (size_t)S_DIM * E_DIM, (size_t)S_DIM * E_DIM, (size_t)S_DIM * S_DIM);

  // softmax rows, in-place bf16
  softmax_k<<<B_DIM * S_DIM, 256, 0, stream>>>(scoresB);

  // V transpose per batch
  transpose_k<<<dim3(E_DIM / 32, S_DIM / 32, B_DIM), 256, 0, stream>>>(Vb, Vt);

  // ctx[b] = P V, batched over z (writes over Qb; P + Vt still live)
  dim3 gPV(E_DIM / 128, S_DIM / 256, B_DIM);
  gemm256_k<bf16, false><<<gPV, 512, 0, stream>>>(
      scoresB, S_DIM, Vt, S_DIM, ctx, E_DIM, S_DIM, E_DIM, S_DIM,
      nullptr, nullptr, 0, 1.0f,
      (size_t)S_DIM * S_DIM, (size_t)S_DIM * E_DIM, (size_t)S_DIM * E_DIM);

  // h = src + ctx @ Wo^T + bo   (fp32, into d_out)
  gemm256_k<float, false><<<gQKV, 512, 0, stream>>>(ctx, E_DIM, wo, E_DIM, h, E_DIM,
      NTOK, E_DIM, E_DIM, Wo_b, src, E_DIM, 1.0f, 0, 0, 0);

  // LN2 (reads h=d_out, writes hn over Kb)
  layernorm_k<bf16><<<NTOK, 256, 0, stream>>>(h, hn, g2, b2);

  // f1 = relu(hn @ W1^T + b1)   (writes over Vb/Vt/scores span)
  dim3 gF1(FF_DIM / 128, NTOK / 256);
  gemm256_k<bf16, true><<<gF1, 512, 0, stream>>>(hn, E_DIM, w1, E_DIM, f1, FF_DIM,
      NTOK, FF_DIM, E_DIM, W1_b, nullptr, 0, 1.0f, 0, 0, 0);

  // out = h + f1 @ W2^T + b2   (fp32, resid == C: per-element read-then-write)
  gemm256_k<float, false><<<gQKV, 512, 0, stream>>>(f1, FF_DIM, w2, FF_DIM, out, E_DIM,
      NTOK, E_DIM, FF_DIM, W2_b, h, E_DIM, 1.0f, 0, 0, 0);

  // LN3 in-place
  layernorm_k<float><<<NTOK, 256, 0, stream>>>(out, out, g3, b3);
}